// Round 17
// baseline (820.703 us; speedup 1.0000x reference)
//
#include <hip/hip_runtime.h>
#include <hip/hip_bf16.h>
#include <stdint.h>

// GCN pose: fused per-sample chain. 64*243=15552 samples, 17 joints, hidden 256, 4 layers.
// Round 17: r16 with the permlane32_swap REVERTED to proven __shfl_xor (r16's absmax 1.56
// matched the pre-committed "permlane direction wrong" signature — 2nd failed attempt at
// that instruction; abandoning it). Kept from r16: (a) mix accumulates into reused acc,
// (b) residual in f32 hold[2] regs (removes 32 ds_read_u16/wave/layer; f32-exact residual).
// hold+acc = 64 accumulator regs = r15's acc+m2 — no new register pressure.

#define J17   17
#define HID   256
#define NLAY  4
#define NSAMP 15552
#define SPW   3
#define RUSE  51         // SPW*17 used rows
#define RPAD  64         // padded rows (2 row-tiles of 32)
#define NWG   5184       // NSAMP/SPW exactly

typedef __attribute__((ext_vector_type(4)))  short  short4v;
typedef __attribute__((ext_vector_type(8)))  short  short8;
typedef __attribute__((ext_vector_type(16))) float  float16;

__device__ __forceinline__ unsigned short f2bf(float f){
  return __bfloat16_as_ushort(__float2bfloat16(f));   // v_cvt, RNE
}
__device__ __forceinline__ float bf2f(unsigned short b){
  return __builtin_bit_cast(float, ((unsigned)b) << 16);
}

// ---------------- prep ----------------
// pret_b (512 KB): [t(64)][kh(2)][c(256)][j(8)], value = bf16(W[t>>4][k][c]),
//                k = (t&15)*16 + kh*8 + j
// pret_in (8 KB): [kh(2)][c(256)][j(8)] = bf16(w_in[k][c]), k = kh*8+j (<3 else 0)
// pret_out (32 KB): [hl(2)][ks(16)][kh(2)][col(32)][j(8)] = split(w_out[k][col], hl)
// pret_a (8 KB): [rt(2)][ks(4)][lane(64)][j(8)] = bf16(Ahat_bd[R][K]),
//                R = rt*32 + (lane&31), K = ks*16 + (lane>>5)*8 + j
__global__ __launch_bounds__(256)
void gcn_prep(const float* __restrict__ adj, const float* __restrict__ Ws,
              const float* __restrict__ w_in, const float* __restrict__ w_out,
              unsigned short* __restrict__ pret_a, unsigned short* __restrict__ pret_in,
              unsigned short* __restrict__ pret_out, unsigned short* __restrict__ pret_b)
{
  if (blockIdx.x < 1024){
    const int e  = blockIdx.x*256 + threadIdx.x;
    const int j  = e & 7, cc = (e >> 3) & 255, khh = (e >> 11) & 1, t = e >> 12;
    const int k  = (t & 15)*16 + khh*8 + j;
    pret_b[(t*2 + khh)*2048 + cc*8 + j] = f2bf(Ws[(t >> 4)*65536 + k*256 + cc]);
  } else {
    const int tid = threadIdx.x;
    __shared__ float Ash[289];
    for (int t = tid; t < 289; t += 256){
      const int j = t/17, k2 = t%17;
      float dj = 1e-5f, dk = 1e-5f;
      for (int m=0;m<17;++m){ dj += adj[j*17+m]; dk += adj[k2*17+m]; }
      Ash[t] = adj[t] / (sqrtf(dj)*sqrtf(dk));
    }
    __syncthreads();
    for (int e = tid; e < 4096; e += 256){
      const int j = e & 7, cc = (e >> 3) & 255, khh = e >> 11;
      const int k = khh*8 + j;
      pret_in[e] = (k < 3) ? f2bf(w_in[k*256 + cc]) : (unsigned short)0;
    }
    for (int e = tid; e < 8192; e += 256){
      const int j = e & 7, col = (e >> 3) & 31, khh = (e >> 8) & 1, ks = e >> 9;
      const int k = ks*16 + khh*8 + j;
      const float w = (col < 3) ? w_out[k*3 + col] : 0.0f;
      const unsigned short hi = f2bf(w);
      const int idx = ((ks*2 + khh)*32 + col)*8 + j;
      pret_out[idx]        = hi;
      pret_out[idx + 8192] = f2bf(w - bf2f(hi));
    }
    // Ahat_bd fragments, single bf16
    for (int e = tid; e < 4096; e += 256){
      const int j = e & 7, lane = (e >> 3) & 63;
      const int ks = (e >> 9) & 3, rt = (e >> 11) & 1;
      const int R = rt*32 + (lane & 31);
      const int K = ks*16 + (lane >> 5)*8 + j;
      float v = 0.0f;
      if (R < RUSE && K < RUSE && (R/17) == (K/17))
        v = Ash[(R%17)*17 + (K%17)];
      pret_a[e] = f2bf(v);
    }
  }
}

__global__ __launch_bounds__(512, 4)
void gcn_main(const float* __restrict__ x, const float* __restrict__ b_in,
              const float* __restrict__ bs, const float* __restrict__ b_out,
              const unsigned short* __restrict__ pret_a,
              const unsigned short* __restrict__ pret_in,
              const unsigned short* __restrict__ pret_out,
              const unsigned short* __restrict__ pret_b,
              float* __restrict__ out)
{
  __shared__ unsigned short h[2*RPAD*HID];          // 64 KB: two 32 KB buffers
  __shared__ unsigned short al[4096];               // 8 KB Ahat_bd frags (bf16)
  unsigned short* xt = h + RPAD*HID;                // x-tile aliases buf1 (dead by mix0)

  const int tid  = threadIdx.x;
  const int lane = tid & 63;
  const int wid  = tid >> 6;
  const int kh   = lane >> 5;
  const int l31  = lane & 31;
  const int c    = wid*32 + l31;
  const int wg   = blockIdx.x;

  const char* h_b = (const char*)h;

  // ---- B prefetch: single bf16 W frags straight from global (L2-resident) ----
  const unsigned short* pb = pret_b + kh*2048 + c*8;
  short8 BA, BB;                                    // W frag for one k-step
  auto loadB = [&](int t, short8& d){
    d = *(const short8*)(pb + t*4096);
  };
  loadB(0, BA);
  const short8 BI = *(const short8*)(pret_in + kh*2048 + c*8);

  // ---- stage x tile (in buf1 alias) + Ahat_bd frags -> LDS ----
  {
    const int r = tid >> 3, k4 = (tid & 7) << 2;
    short4v v = (short4v)0;
    if (r < RUSE && k4 == 0){
      const int s = r/17, j = r - s*17;
      const float* xb = x + (size_t)(wg*SPW + s)*51 + j*3;
      v.x = (short)f2bf(xb[0]); v.y = (short)f2bf(xb[1]); v.z = (short)f2bf(xb[2]);
    }
    *(short4v*)(xt + r*32 + k4) = v;
    short8* al8s = (short8*)al;
    const short8* pa8 = (const short8*)pret_a;
    al8s[tid] = pa8[tid];                           // 512 x 16B = 8 KB
  }
  __syncthreads();

  // ---- input projection as MFMA: h0 = x @ w_in + b_in -> buf0 (bf16) ----
  float16 acc[2];
  float16 hold[2];                                  // f32 residual, C-layout slots
  {
    const float bc = b_in[c];
#pragma unroll
    for (int rt=0; rt<2; ++rt)
#pragma unroll
    for (int q=0; q<16; ++q) acc[rt][q] = bc;
#pragma unroll
    for (int rt=0; rt<2; ++rt){
      const short8 Ax = *(const short8*)(xt + (rt*32 + l31)*32 + kh*8);
      acc[rt] = __builtin_amdgcn_mfma_f32_32x32x16_bf16(Ax, BI, acc[rt], 0,0,0);
    }
#pragma unroll
    for (int rt=0; rt<2; ++rt)
#pragma unroll
    for (int q=0; q<16; ++q){
      const int r  = rt*32 + (q&3) + 8*(q>>2) + 4*kh;
      const int hb = (r << 9) + ((2*c) ^ ((r & 31) << 4));
      hold[rt][q] = acc[rt][q];
      h[hb >> 1] = f2bf(acc[rt][q]);
    }
  }
  __syncthreads();

  // ---- layers: read buf[l&1], write buf[(l+1)&1]; ONE barrier per layer ----
#pragma unroll 1
  for (int layer=0; layer<NLAY; ++layer){
    const char* hr = h_b + (size_t)((layer & 1) * (RPAD*HID*2));
#pragma unroll
    for (int rt=0; rt<2; ++rt)
#pragma unroll
    for (int q=0; q<16; ++q) acc[rt][q] = 0.0f;

    auto step = [&](int ksl, const short8 B){
      short8 Ah[2];
#pragma unroll
      for (int rt=0; rt<2; ++rt){
        const int r   = rt*32 + l31;
        const int off = (r << 9) + ((ksl*32 + kh*16) ^ ((r & 31) << 4));
        Ah[rt] = *(const short8*)(hr + off);
      }
#pragma unroll
      for (int rt=0; rt<2; ++rt)
        acc[rt] = __builtin_amdgcn_mfma_f32_32x32x16_bf16(Ah[rt], B, acc[rt], 0,0,0);
    };

    const int t0 = layer*16;
#pragma unroll
    for (int ks=0; ks<16; ks+=2){
      loadB(t0 + ks + 1, BB);
      step(ks, BA);
      loadB(min(t0 + ks + 2, 63), BA);
      step(ks + 1, BB);
    }

    // ---- repack S (acc, C-layout) into mix B-frags Bs[ks] (k = 16ks+8kh+j) ----
    // half-swap via proven __shfl_xor(32). acc dead after this block -> reused below.
    short8 Bs[4];
#pragma unroll
    for (int ks=0; ks<4; ++ks){
      const int rt = ks >> 1;
      const int lq = ((2*ks) & 3) << 2;        // slots of rows 16ks+i (h0) / +4+i (h1)
      const int hq = ((2*ks + 1) & 3) << 2;    // slots of rows 16ks+8+i (h0) / +12+i (h1)
#pragma unroll
      for (int i=0; i<4; ++i){
        const float lo_v = acc[rt][lq | i];
        const float hi_v = acc[rt][hq | i];
        const float send = kh ? lo_v : hi_v;   // what partner half needs
        const float own  = kh ? hi_v : lo_v;   // what I keep
        const float recv = __shfl_xor(send, 32, 64);
        const float f_i  = kh ? recv : own;    // frag element j=i
        const float f_i4 = kh ? own  : recv;   // frag element j=4+i
        Bs[ks][i]     = (short)f2bf(f_i);
        Bs[ks][4 + i] = (short)f2bf(f_i4);
      }
    }

    // ---- mix MFMA into REUSED acc: acc = Ahat_bd @ S, fenced liveness ----
#pragma unroll
    for (int rt2=0; rt2<2; ++rt2)
#pragma unroll
    for (int q=0; q<16; ++q) acc[rt2][q] = 0.0f;
    __builtin_amdgcn_sched_barrier(0);
    const short8* al8 = (const short8*)al;
#pragma unroll
    for (int ks=0; ks<4; ++ks){
      {
        const short8 Am = al8[(0*4 + ks)*64 + lane];
        acc[0] = __builtin_amdgcn_mfma_f32_32x32x16_bf16(Am, Bs[ks], acc[0], 0,0,0);
      }
      __builtin_amdgcn_sched_barrier(0);
      {
        const short8 Am = al8[(1*4 + ks)*64 + lane];
        acc[1] = __builtin_amdgcn_mfma_f32_32x32x16_bf16(Am, Bs[ks], acc[1], 0,0,0);
      }
      __builtin_amdgcn_sched_barrier(0);
    }

    // ---- pointwise: h' = relu(acc + bias) + hold; hold kept in f32 regs ----
    {
      const float bsv = bs[layer*256 + c];
      unsigned short* hw = h + (((layer & 1) ^ 1) * RPAD*HID);
#pragma unroll
      for (int rt2=0; rt2<2; ++rt2)
#pragma unroll
      for (int q=0; q<16; ++q){
        const int r   = rt2*32 + (q&3) + 8*(q>>2) + 4*kh;
        const int off = (r << 9) + ((2*c) ^ ((r & 31) << 4));
        const float o = fmaxf(acc[rt2][q] + bsv, 0.0f) + hold[rt2][q];
        hold[rt2][q] = o;
        hw[off >> 1] = f2bf(o);
      }
    }
    __syncthreads();
  }

  // ---- output projection as MFMA on wave 0: y = h @ w_out + b_out ----
  if (wid == 0){
    const float bo = (l31 < 3) ? b_out[l31] : 0.0f;
    float16 y[2];
#pragma unroll
    for (int rt=0; rt<2; ++rt)
#pragma unroll
    for (int q=0; q<16; ++q) y[rt][q] = bo;

    const unsigned short* po = pret_out + kh*256 + l31*8;
#pragma unroll
    for (int ks=0; ks<16; ++ks){
      const short8 Bh = *(const short8*)(po + ks*512);
      const short8 Bl = *(const short8*)(po + 8192 + ks*512);
      short8 Ah[2];
#pragma unroll
      for (int rt=0; rt<2; ++rt){
        const int r   = rt*32 + l31;
        const int off = (r << 9) + ((ks*32 + kh*16) ^ ((r & 31) << 4));
        Ah[rt] = *(const short8*)(h_b + off);          // final h is buf0
      }
#pragma unroll
      for (int rt=0; rt<2; ++rt){
        y[rt] = __builtin_amdgcn_mfma_f32_32x32x16_bf16(Ah[rt], Bh, y[rt], 0,0,0);
        y[rt] = __builtin_amdgcn_mfma_f32_32x32x16_bf16(Ah[rt], Bl, y[rt], 0,0,0);
      }
    }
#pragma unroll
    for (int rt=0; rt<2; ++rt)
#pragma unroll
    for (int q=0; q<16; ++q){
      const int r0 = rt*32 + (q&3) + 8*(q>>2);
      const int r  = r0 + 4*kh;
      if (r < RUSE && l31 < 3){
        const int s = r/17, jj = r - s*17;
        out[((size_t)(wg*SPW + s)*17 + jj)*3 + l31] = y[rt][q];
      }
    }
  }
}

extern "C" void kernel_launch(void* const* d_in, const int* in_sizes, int n_in,
                              void* d_out, int out_size, void* d_ws, size_t ws_size,
                              hipStream_t stream)
{
  const float* x     = (const float*)d_in[0];
  const float* adj   = (const float*)d_in[1];
  const float* w_in  = (const float*)d_in[2];
  const float* b_in  = (const float*)d_in[3];
  const float* Ws    = (const float*)d_in[4];
  const float* bs    = (const float*)d_in[5];
  const float* w_out = (const float*)d_in[6];
  const float* b_out = (const float*)d_in[7];
  float* out = (float*)d_out;

  unsigned short* pret_a   = (unsigned short*)d_ws;                      // 8 KB
  unsigned short* pret_in  = (unsigned short*)((char*)d_ws + 8192);     // 8 KB
  unsigned short* pret_out = (unsigned short*)((char*)d_ws + 16384);    // 32 KB
  unsigned short* pret_b   = (unsigned short*)((char*)d_ws + 65536);    // 512 KB

  hipLaunchKernelGGL(gcn_prep, dim3(1025), dim3(256), 0, stream,
                     adj, Ws, w_in, w_out, pret_a, pret_in, pret_out, pret_b);
  hipLaunchKernelGGL(gcn_main, dim3(NWG), dim3(512), 0, stream,
                     x, b_in, bs, b_out, pret_a, pret_in, pret_out, pret_b, out);
}

// Round 18
// 319.432 us; speedup vs baseline: 2.5693x; 2.5693x over previous
//
#include <hip/hip_runtime.h>
#include <hip/hip_bf16.h>
#include <stdint.h>

// GCN pose: fused per-sample chain. 64*243=15552 samples, 17 joints, hidden 256, 4 layers.
// Round 18: RESTORE r15 verbatim (best known: 319.9 us, absmax 0.015625, WRITE 3.2 MB).
// r15 is a local optimum wedged at the 128-reg/4-wave/2-WG point: every register
// perturbation in either direction (r12 -regs, r13 +16 persistent, r14 +32 phase-local,
// r16/r17 +32 persistent) spilled or starved. Single-pass bf16 W GEMM, single-pass bf16
// Ahat MFMA mix, h double-buffer, 1 barrier/layer, fenced mix liveness, 512 thr.

#define J17   17
#define HID   256
#define NLAY  4
#define NSAMP 15552
#define SPW   3
#define RUSE  51         // SPW*17 used rows
#define RPAD  64         // padded rows (2 row-tiles of 32)
#define NWG   5184       // NSAMP/SPW exactly

typedef __attribute__((ext_vector_type(4)))  short  short4v;
typedef __attribute__((ext_vector_type(8)))  short  short8;
typedef __attribute__((ext_vector_type(16))) float  float16;

__device__ __forceinline__ unsigned short f2bf(float f){
  return __bfloat16_as_ushort(__float2bfloat16(f));   // v_cvt, RNE
}
__device__ __forceinline__ float bf2f(unsigned short b){
  return __builtin_bit_cast(float, ((unsigned)b) << 16);
}

// ---------------- prep ----------------
// pret_b (512 KB): [t(64)][kh(2)][c(256)][j(8)], value = bf16(W[t>>4][k][c]),
//                k = (t&15)*16 + kh*8 + j
// pret_in (8 KB): [kh(2)][c(256)][j(8)] = bf16(w_in[k][c]), k = kh*8+j (<3 else 0)
// pret_out (32 KB): [hl(2)][ks(16)][kh(2)][col(32)][j(8)] = split(w_out[k][col], hl)
// pret_a (8 KB): [rt(2)][ks(4)][lane(64)][j(8)] = bf16(Ahat_bd[R][K]),
//                R = rt*32 + (lane&31), K = ks*16 + (lane>>5)*8 + j
__global__ __launch_bounds__(256)
void gcn_prep(const float* __restrict__ adj, const float* __restrict__ Ws,
              const float* __restrict__ w_in, const float* __restrict__ w_out,
              unsigned short* __restrict__ pret_a, unsigned short* __restrict__ pret_in,
              unsigned short* __restrict__ pret_out, unsigned short* __restrict__ pret_b)
{
  if (blockIdx.x < 1024){
    const int e  = blockIdx.x*256 + threadIdx.x;
    const int j  = e & 7, cc = (e >> 3) & 255, khh = (e >> 11) & 1, t = e >> 12;
    const int k  = (t & 15)*16 + khh*8 + j;
    pret_b[(t*2 + khh)*2048 + cc*8 + j] = f2bf(Ws[(t >> 4)*65536 + k*256 + cc]);
  } else {
    const int tid = threadIdx.x;
    __shared__ float Ash[289];
    for (int t = tid; t < 289; t += 256){
      const int j = t/17, k2 = t%17;
      float dj = 1e-5f, dk = 1e-5f;
      for (int m=0;m<17;++m){ dj += adj[j*17+m]; dk += adj[k2*17+m]; }
      Ash[t] = adj[t] / (sqrtf(dj)*sqrtf(dk));
    }
    __syncthreads();
    for (int e = tid; e < 4096; e += 256){
      const int j = e & 7, cc = (e >> 3) & 255, khh = e >> 11;
      const int k = khh*8 + j;
      pret_in[e] = (k < 3) ? f2bf(w_in[k*256 + cc]) : (unsigned short)0;
    }
    for (int e = tid; e < 8192; e += 256){
      const int j = e & 7, col = (e >> 3) & 31, khh = (e >> 8) & 1, ks = e >> 9;
      const int k = ks*16 + khh*8 + j;
      const float w = (col < 3) ? w_out[k*3 + col] : 0.0f;
      const unsigned short hi = f2bf(w);
      const int idx = ((ks*2 + khh)*32 + col)*8 + j;
      pret_out[idx]        = hi;
      pret_out[idx + 8192] = f2bf(w - bf2f(hi));
    }
    // Ahat_bd fragments, single bf16
    for (int e = tid; e < 4096; e += 256){
      const int j = e & 7, lane = (e >> 3) & 63;
      const int ks = (e >> 9) & 3, rt = (e >> 11) & 1;
      const int R = rt*32 + (lane & 31);
      const int K = ks*16 + (lane >> 5)*8 + j;
      float v = 0.0f;
      if (R < RUSE && K < RUSE && (R/17) == (K/17))
        v = Ash[(R%17)*17 + (K%17)];
      pret_a[e] = f2bf(v);
    }
  }
}

__global__ __launch_bounds__(512, 4)
void gcn_main(const float* __restrict__ x, const float* __restrict__ b_in,
              const float* __restrict__ bs, const float* __restrict__ b_out,
              const unsigned short* __restrict__ pret_a,
              const unsigned short* __restrict__ pret_in,
              const unsigned short* __restrict__ pret_out,
              const unsigned short* __restrict__ pret_b,
              float* __restrict__ out)
{
  __shared__ unsigned short h[2*RPAD*HID];          // 64 KB: two 32 KB buffers
  __shared__ unsigned short al[4096];               // 8 KB Ahat_bd frags (bf16)
  unsigned short* xt = h + RPAD*HID;                // x-tile aliases buf1 (dead by mix0)

  const int tid  = threadIdx.x;
  const int lane = tid & 63;
  const int wid  = tid >> 6;
  const int kh   = lane >> 5;
  const int l31  = lane & 31;
  const int c    = wid*32 + l31;
  const int wg   = blockIdx.x;

  const char* h_b = (const char*)h;

  // ---- B prefetch: single bf16 W frags straight from global (L2-resident) ----
  const unsigned short* pb = pret_b + kh*2048 + c*8;
  short8 BA, BB;                                    // W frag for one k-step
  auto loadB = [&](int t, short8& d){
    d = *(const short8*)(pb + t*4096);
  };
  loadB(0, BA);
  const short8 BI = *(const short8*)(pret_in + kh*2048 + c*8);

  // ---- stage x tile (in buf1 alias) + Ahat_bd frags -> LDS ----
  {
    const int r = tid >> 3, k4 = (tid & 7) << 2;
    short4v v = (short4v)0;
    if (r < RUSE && k4 == 0){
      const int s = r/17, j = r - s*17;
      const float* xb = x + (size_t)(wg*SPW + s)*51 + j*3;
      v.x = (short)f2bf(xb[0]); v.y = (short)f2bf(xb[1]); v.z = (short)f2bf(xb[2]);
    }
    *(short4v*)(xt + r*32 + k4) = v;
    short8* al8s = (short8*)al;
    const short8* pa8 = (const short8*)pret_a;
    al8s[tid] = pa8[tid];                           // 512 x 16B = 8 KB
  }
  __syncthreads();

  // ---- input projection as MFMA: h0 = x @ w_in + b_in -> buf0 (bf16) ----
  float16 acc[2];
  {
    const float bc = b_in[c];
#pragma unroll
    for (int rt=0; rt<2; ++rt)
#pragma unroll
    for (int q=0; q<16; ++q) acc[rt][q] = bc;
#pragma unroll
    for (int rt=0; rt<2; ++rt){
      const short8 Ax = *(const short8*)(xt + (rt*32 + l31)*32 + kh*8);
      acc[rt] = __builtin_amdgcn_mfma_f32_32x32x16_bf16(Ax, BI, acc[rt], 0,0,0);
    }
#pragma unroll
    for (int rt=0; rt<2; ++rt)
#pragma unroll
    for (int q=0; q<16; ++q){
      const int r  = rt*32 + (q&3) + 8*(q>>2) + 4*kh;
      const int hb = (r << 9) + ((2*c) ^ ((r & 31) << 4));
      h[hb >> 1] = f2bf(acc[rt][q]);
    }
  }
  __syncthreads();

  // ---- layers: read buf[l&1], write buf[(l+1)&1]; ONE barrier per layer ----
#pragma unroll 1
  for (int layer=0; layer<NLAY; ++layer){
    const char* hr = h_b + (size_t)((layer & 1) * (RPAD*HID*2));
    const unsigned short* hru = (const unsigned short*)hr;
#pragma unroll
    for (int rt=0; rt<2; ++rt)
#pragma unroll
    for (int q=0; q<16; ++q) acc[rt][q] = 0.0f;

    auto step = [&](int ksl, const short8 B){
      short8 Ah[2];
#pragma unroll
      for (int rt=0; rt<2; ++rt){
        const int r   = rt*32 + l31;
        const int off = (r << 9) + ((ksl*32 + kh*16) ^ ((r & 31) << 4));
        Ah[rt] = *(const short8*)(hr + off);
      }
#pragma unroll
      for (int rt=0; rt<2; ++rt)
        acc[rt] = __builtin_amdgcn_mfma_f32_32x32x16_bf16(Ah[rt], B, acc[rt], 0,0,0);
    };

    const int t0 = layer*16;
#pragma unroll
    for (int ks=0; ks<16; ks+=2){
      loadB(t0 + ks + 1, BB);
      step(ks, BA);
      loadB(min(t0 + ks + 2, 63), BA);
      step(ks + 1, BB);
    }

    // ---- repack S (acc, C-layout) into mix B-frags Bs[ks] (k = 16ks+8kh+j) ----
    // acc is fully dead after this block (16 bf16x8 regs replace 32 f32).
    short8 Bs[4];
#pragma unroll
    for (int ks=0; ks<4; ++ks){
      const int rt = ks >> 1;
      const int lq = ((2*ks) & 3) << 2;        // slots of rows 16ks+i (h0) / +4+i (h1)
      const int hq = ((2*ks + 1) & 3) << 2;    // slots of rows 16ks+8+i (h0) / +12+i (h1)
#pragma unroll
      for (int i=0; i<4; ++i){
        const float lo_v = acc[rt][lq | i];
        const float hi_v = acc[rt][hq | i];
        const float send = kh ? lo_v : hi_v;   // what partner half needs
        const float own  = kh ? hi_v : lo_v;   // what I keep
        const float recv = __shfl_xor(send, 32, 64);
        const float f_i  = kh ? recv : own;    // frag element j=i
        const float f_i4 = kh ? own  : recv;   // frag element j=4+i
        Bs[ks][i]     = (short)f2bf(f_i);
        Bs[ks][4 + i] = (short)f2bf(f_i4);
      }
    }

    // ---- mix MFMA: m2 = Ahat_bd @ S (single bf16 pass), fenced liveness ----
    float16 m2[2];
#pragma unroll
    for (int rt2=0; rt2<2; ++rt2)
#pragma unroll
    for (int q=0; q<16; ++q) m2[rt2][q] = 0.0f;
    __builtin_amdgcn_sched_barrier(0);
    const short8* al8 = (const short8*)al;
#pragma unroll
    for (int ks=0; ks<4; ++ks){
      {
        const short8 Am = al8[(0*4 + ks)*64 + lane];
        m2[0] = __builtin_amdgcn_mfma_f32_32x32x16_bf16(Am, Bs[ks], m2[0], 0,0,0);
      }
      __builtin_amdgcn_sched_barrier(0);
      {
        const short8 Am = al8[(1*4 + ks)*64 + lane];
        m2[1] = __builtin_amdgcn_mfma_f32_32x32x16_bf16(Am, Bs[ks], m2[1], 0,0,0);
      }
      __builtin_amdgcn_sched_barrier(0);
    }

    // ---- pointwise: h' = relu(m2 + bias) + h  (all slots, pad rows stay finite) ----
    {
      const float bsv = bs[layer*256 + c];
      unsigned short* hw = h + (((layer & 1) ^ 1) * RPAD*HID);
#pragma unroll
      for (int rt2=0; rt2<2; ++rt2)
#pragma unroll
      for (int q=0; q<16; ++q){
        const int r   = rt2*32 + (q&3) + 8*(q>>2) + 4*kh;
        const int off = (r << 9) + ((2*c) ^ ((r & 31) << 4));
        const float o = fmaxf(m2[rt2][q] + bsv, 0.0f) + bf2f(hru[off >> 1]);
        hw[off >> 1] = f2bf(o);
      }
    }
    __syncthreads();
  }

  // ---- output projection as MFMA on wave 0: y = h @ w_out + b_out ----
  if (wid == 0){
    const float bo = (l31 < 3) ? b_out[l31] : 0.0f;
    float16 y[2];
#pragma unroll
    for (int rt=0; rt<2; ++rt)
#pragma unroll
    for (int q=0; q<16; ++q) y[rt][q] = bo;

    const unsigned short* po = pret_out + kh*256 + l31*8;
#pragma unroll
    for (int ks=0; ks<16; ++ks){
      const short8 Bh = *(const short8*)(po + ks*512);
      const short8 Bl = *(const short8*)(po + 8192 + ks*512);
      short8 Ah[2];
#pragma unroll
      for (int rt=0; rt<2; ++rt){
        const int r   = rt*32 + l31;
        const int off = (r << 9) + ((ks*32 + kh*16) ^ ((r & 31) << 4));
        Ah[rt] = *(const short8*)(h_b + off);          // final h is buf0
      }
#pragma unroll
      for (int rt=0; rt<2; ++rt){
        y[rt] = __builtin_amdgcn_mfma_f32_32x32x16_bf16(Ah[rt], Bh, y[rt], 0,0,0);
        y[rt] = __builtin_amdgcn_mfma_f32_32x32x16_bf16(Ah[rt], Bl, y[rt], 0,0,0);
      }
    }
#pragma unroll
    for (int rt=0; rt<2; ++rt)
#pragma unroll
    for (int q=0; q<16; ++q){
      const int r0 = rt*32 + (q&3) + 8*(q>>2);
      const int r  = r0 + 4*kh;
      if (r < RUSE && l31 < 3){
        const int s = r/17, jj = r - s*17;
        out[((size_t)(wg*SPW + s)*17 + jj)*3 + l31] = y[rt][q];
      }
    }
  }
}

extern "C" void kernel_launch(void* const* d_in, const int* in_sizes, int n_in,
                              void* d_out, int out_size, void* d_ws, size_t ws_size,
                              hipStream_t stream)
{
  const float* x     = (const float*)d_in[0];
  const float* adj   = (const float*)d_in[1];
  const float* w_in  = (const float*)d_in[2];
  const float* b_in  = (const float*)d_in[3];
  const float* Ws    = (const float*)d_in[4];
  const float* bs    = (const float*)d_in[5];
  const float* w_out = (const float*)d_in[6];
  const float* b_out = (const float*)d_in[7];
  float* out = (float*)d_out;

  unsigned short* pret_a   = (unsigned short*)d_ws;                      // 8 KB
  unsigned short* pret_in  = (unsigned short*)((char*)d_ws + 8192);     // 8 KB
  unsigned short* pret_out = (unsigned short*)((char*)d_ws + 16384);    // 32 KB
  unsigned short* pret_b   = (unsigned short*)((char*)d_ws + 65536);    // 512 KB

  hipLaunchKernelGGL(gcn_prep, dim3(1025), dim3(256), 0, stream,
                     adj, Ws, w_in, w_out, pret_a, pret_in, pret_out, pret_b);
  hipLaunchKernelGGL(gcn_main, dim3(NWG), dim3(512), 0, stream,
                     x, b_in, bs, b_out, pret_a, pret_in, pret_out, pret_b, out);
}